// Round 6
// baseline (356.296 us; speedup 1.0000x reference)
//
#include <hip/hip_runtime.h>

#define BB   4
#define NHID 128
#define LL   1024
#define NH   10
#define HD   10
#define DD   100
#define SCALE 0.31622776601683794f   // 1/sqrt(10)

typedef float vfloat4 __attribute__((ext_vector_type(4)));

// -------- K1: q projection -> kT buffer (B, NH, HD, L), 4 channels/block ----
__global__ __launch_bounds__(256) void k_qproj(
    const float* __restrict__ x, const float* __restrict__ wq_w,
    const float* __restrict__ wq_b, float* __restrict__ kT) {
  const int l  = blockIdx.x * 256 + threadIdx.x;
  const int c0 = blockIdx.y * 4;
  const int b  = blockIdx.z;
  float acc[4];
  #pragma unroll
  for (int i = 0; i < 4; ++i) acc[i] = wq_b[c0 + i];
  const float* xb = x + (size_t)b * NHID * LL + l;
  const float* w0 = wq_w + (size_t)c0 * NHID;
  #pragma unroll 4
  for (int h = 0; h < NHID; ++h) {
    float xv = xb[(size_t)h * LL];             // coalesced across threads
    #pragma unroll
    for (int i = 0; i < 4; ++i) acc[i] += w0[i * NHID + h] * xv;  // scalar loads
  }
  #pragma unroll
  for (int i = 0; i < 4; ++i) {
    int c = c0 + i, n = c / HD, d = c % HD;
    kT[(((size_t)(b * NH + n)) * HD + d) * LL + l] = acc[i];      // coalesced
  }
}

// ---- K1b: esj = exp((k.w2)*scale); row factor exp(si) cancels in softmax ----
__global__ __launch_bounds__(256) void k_edgeproj(
    const float* __restrict__ kT, const float* __restrict__ we_w,
    float* __restrict__ esj) {
  const int idx = blockIdx.x * 256 + threadIdx.x;   // over B*NH*L = 40960
  const int bn = idx >> 10, l = idx & (LL - 1);
  const float* kp = kT + (size_t)bn * HD * LL + l;
  float s2 = 0.f;
  #pragma unroll
  for (int d = 0; d < HD; ++d) s2 += kp[(size_t)d * LL] * we_w[HD + d];  // coalesced
  esj[idx] = __expf(s2 * SCALE);
}

// ---- PV cross-lane reduce (d=0..9 padded to 16) + att store, 4 rows ----
__device__ __forceinline__ void pv_reduce_store(
    float part[4][HD], const float* inv, float* __restrict__ att,
    int bn, int i0, int lane) {
  const bool c5 = (lane & 32) != 0;
  const bool c4 = (lane & 16) != 0;
  const bool c3 = (lane & 8) != 0;
  const bool c2 = (lane & 4) != 0;
  #pragma unroll
  for (int r = 0; r < 4; ++r) {
    float pv[16];
    #pragma unroll
    for (int d = 0; d < HD; ++d) pv[d] = part[r][d];
    #pragma unroll
    for (int d = HD; d < 16; ++d) pv[d] = 0.f;
    #pragma unroll
    for (int i = 0; i < 8; ++i) {
      float snd = c5 ? pv[i] : pv[i + 8];
      float kp  = c5 ? pv[i + 8] : pv[i];
      pv[i] = kp + __shfl_xor(snd, 32, 64);
    }
    #pragma unroll
    for (int i = 0; i < 4; ++i) {
      float snd = c4 ? pv[i] : pv[i + 4];
      float kp  = c4 ? pv[i + 4] : pv[i];
      pv[i] = kp + __shfl_xor(snd, 16, 64);
    }
    #pragma unroll
    for (int i = 0; i < 2; ++i) {
      float snd = c3 ? pv[i] : pv[i + 2];
      float kp  = c3 ? pv[i + 2] : pv[i];
      pv[i] = kp + __shfl_xor(snd, 8, 64);
    }
    {
      float snd = c2 ? pv[0] : pv[1];
      float kp  = c2 ? pv[1] : pv[0];
      pv[0] = kp + __shfl_xor(snd, 4, 64);
    }
    pv[0] += __shfl_xor(pv[0], 2, 64);
    pv[0] += __shfl_xor(pv[0], 1, 64);
    float g = __shfl(pv[0], lane * 4, 64);   // lane l holds d=(l>>2)&15
    if (lane < HD)
      att[((size_t)bn * LL + (i0 + r)) * HD + lane] = g * inv[r];
  }
}

// ---- K2: fused mask+softmax+PV, exp-free, 2 heads/block share one edge read.
// alpha[i,j] = mask[i,j]*esj[j] / sum_j mask[i,j]*esj[j]
// block = 512 (8 waves), 4 rows/wave -> 32 rows, heads (2*hp, 2*hp+1).
__global__ __launch_bounds__(512, 3) void k_attn(
    const float* __restrict__ kT, const float* __restrict__ esj,
    const int* __restrict__ edge,
    float* __restrict__ alpha_out, float* __restrict__ att) {
  const int t    = threadIdx.x;
  const int lane = t & 63;
  const int wid  = t >> 6;
  const int rt   = blockIdx.x;        // 0..31
  const int hp   = blockIdx.y;        // 0..4
  const int b    = blockIdx.z;        // 0..3
  const int bn0  = b * NH + hp * 2;   // bn0, bn0+1 contiguous in kT
  const int i0   = rt * 32 + wid * 4;

  __shared__ float ksT2[2 * HD * LL];   // 80 KB: kT for both heads, d-major
  {
    const float4* src = (const float4*)(kT + (size_t)bn0 * (HD * LL));
    float4* dst = (float4*)ksT2;
    #pragma unroll
    for (int idx = t; idx < (2 * HD * LL) / 4; idx += 512) dst[idx] = src[idx];
  }
  vfloat4 esv[2][4];                    // esj, j = m*256 + lane*4 + q
  {
    #pragma unroll
    for (int h = 0; h < 2; ++h) {
      const vfloat4* sp = (const vfloat4*)(esj + (size_t)(bn0 + h) * LL);
      #pragma unroll
      for (int m = 0; m < 4; ++m) esv[h][m] = sp[m * 64 + lane];
    }
  }
  __syncthreads();

  // ---- edge loaded ONCE for both heads; compressed to 16 bits/row ----
  const int* ebase = edge + (size_t)b * LL * LL + (size_t)i0 * LL;
  unsigned mask[4] = {0u, 0u, 0u, 0u};
  #pragma unroll
  for (int m = 0; m < 4; ++m) {
    #pragma unroll
    for (int r = 0; r < 4; ++r) {
      int4 e = ((const int4*)(ebase + (size_t)r * LL))[m * 64 + lane];  // coalesced
      mask[r] |= ((e.x ? 1u : 0u) | (e.y ? 2u : 0u) |
                  (e.z ? 4u : 0u) | (e.w ? 8u : 0u)) << (m * 4);
    }
  }

  #pragma unroll
  for (int h = 0; h < 2; ++h) {
    const int bn = bn0 + h;
    const float* ksT = ksT2 + h * (HD * LL);

    // denominators + unnormalized PV
    float part[4][HD];
    float denom[4];
    #pragma unroll
    for (int r = 0; r < 4; ++r) {
      denom[r] = 0.f;
      #pragma unroll
      for (int d = 0; d < HD; ++d) part[r][d] = 0.f;
    }
    #pragma unroll
    for (int m = 0; m < 4; ++m) {
      vfloat4 kv[HD];                       // conflict-free ds_read_b128
      const float* kb = ksT + m * 256 + lane * 4;
      #pragma unroll
      for (int d = 0; d < HD; ++d) kv[d] = *(const vfloat4*)(kb + d * LL);
      const vfloat4 es = esv[h][m];
      #pragma unroll
      for (int r = 0; r < 4; ++r) {
        const unsigned mk = mask[r] >> (m * 4);
        float ax = (mk & 1u) ? es.x : 0.f;
        float ay = (mk & 2u) ? es.y : 0.f;
        float az = (mk & 4u) ? es.z : 0.f;
        float aw = (mk & 8u) ? es.w : 0.f;
        denom[r] += (ax + ay) + (az + aw);
        #pragma unroll
        for (int d = 0; d < HD; ++d)
          part[r][d] += ax * kv[d].x + ay * kv[d].y + az * kv[d].z + aw * kv[d].w;
      }
    }
    float inv[4];
    #pragma unroll
    for (int r = 0; r < 4; ++r) {
      float s = denom[r];
      #pragma unroll
      for (int sft = 32; sft >= 1; sft >>= 1) s += __shfl_xor(s, sft, 64);
      inv[r] = __builtin_amdgcn_rcpf(s);
    }

    // alpha stores from mask bits (nontemporal dwordx4, no edge reload)
    float* ap = alpha_out + ((size_t)bn * LL + i0) * LL;
    #pragma unroll
    for (int m = 0; m < 4; ++m) {
      const vfloat4 es = esv[h][m];
      #pragma unroll
      for (int r = 0; r < 4; ++r) {
        const unsigned mk = mask[r] >> (m * 4);
        vfloat4 a;
        a.x = (mk & 1u) ? es.x * inv[r] : 0.f;
        a.y = (mk & 2u) ? es.y * inv[r] : 0.f;
        a.z = (mk & 4u) ? es.z * inv[r] : 0.f;
        a.w = (mk & 8u) ? es.w * inv[r] : 0.f;
        vfloat4* dst = (vfloat4*)(ap + (size_t)r * LL) + m * 64 + lane;
        __builtin_nontemporal_store(a, dst);
      }
    }

    pv_reduce_store(part, inv, att, bn, i0, lane);
  }
}

// ---------------- K3: output projection over scrambled view ----------------
__global__ __launch_bounds__(256) void k_out(
    const float* __restrict__ att, const float* __restrict__ wo_w,
    const float* __restrict__ wo_b, float* __restrict__ ret) {
  const int l  = blockIdx.x * 256 + threadIdx.x;
  const int o0 = blockIdx.y * 4;
  const int b  = blockIdx.z;
  const float* ab = att + (size_t)b * (DD * LL);
  float acc[4];
  #pragma unroll
  for (int oo = 0; oo < 4; ++oo) acc[oo] = wo_b[o0 + oo];
  for (int c = 0; c < DD; ++c) {
    float a = ab[(size_t)c * LL + l];          // coalesced; view(B,-1,L) == linear index
    #pragma unroll
    for (int oo = 0; oo < 4; ++oo) acc[oo] += wo_w[(size_t)(o0 + oo) * DD + c] * a;
  }
  #pragma unroll
  for (int oo = 0; oo < 4; ++oo)
    ret[((size_t)b * NHID + o0 + oo) * LL + l] = acc[oo];
}

extern "C" void kernel_launch(void* const* d_in, const int* in_sizes, int n_in,
                              void* d_out, int out_size, void* d_ws, size_t ws_size,
                              hipStream_t stream) {
  (void)in_sizes; (void)n_in; (void)out_size; (void)ws_size;
  const float* x    = (const float*)d_in[0];
  const int*   edge = (const int*)d_in[1];
  const float* wq_w = (const float*)d_in[2];
  const float* wq_b = (const float*)d_in[3];
  const float* we_w = (const float*)d_in[4];
  const float* wo_w = (const float*)d_in[6];
  const float* wo_b = (const float*)d_in[7];

  float* out       = (float*)d_out;
  float* ret_out   = out;                                  // B*NHID*L
  float* alpha_out = out + (size_t)BB * NHID * LL;         // B*NH*L*L

  float* ws   = (float*)d_ws;
  float* kT   = ws;                                        // B*NH*HD*L = 409600
  float* esj  = kT + (size_t)BB * NH * HD * LL;            // B*NH*L
  float* att  = esj + (size_t)BB * NH * LL;                // B*NH*L*HD

  dim3 g1(LL / 256, DD / 4, BB);
  k_qproj<<<g1, 256, 0, stream>>>(x, wq_w, wq_b, kT);

  k_edgeproj<<<(BB * NH * LL) / 256, 256, 0, stream>>>(kT, we_w, esj);

  dim3 g2(LL / 32, NH / 2, BB);
  k_attn<<<g2, 512, 0, stream>>>(kT, esj, edge, alpha_out, att);

  dim3 g3(LL / 256, NHID / 4, BB);
  k_out<<<g3, 256, 0, stream>>>(att, wo_w, wo_b, ret_out);
}

// Round 7
// 237.790 us; speedup vs baseline: 1.4984x; 1.4984x over previous
//
#include <hip/hip_runtime.h>

#define BB   4
#define NHID 128
#define LL   1024
#define NH   10
#define HD   10
#define DD   100
#define SCALE 0.31622776601683794f   // 1/sqrt(10)

typedef float vfloat4 __attribute__((ext_vector_type(4)));

// -------- K1: q projection -> kT buffer (B, NH, HD, L), 4 channels/block ----
__global__ __launch_bounds__(256) void k_qproj(
    const float* __restrict__ x, const float* __restrict__ wq_w,
    const float* __restrict__ wq_b, float* __restrict__ kT) {
  const int l  = blockIdx.x * 256 + threadIdx.x;
  const int c0 = blockIdx.y * 4;
  const int b  = blockIdx.z;
  float acc[4];
  #pragma unroll
  for (int i = 0; i < 4; ++i) acc[i] = wq_b[c0 + i];
  const float* xb = x + (size_t)b * NHID * LL + l;
  const float* w0 = wq_w + (size_t)c0 * NHID;
  #pragma unroll 4
  for (int h = 0; h < NHID; ++h) {
    float xv = xb[(size_t)h * LL];             // coalesced across threads
    #pragma unroll
    for (int i = 0; i < 4; ++i) acc[i] += w0[i * NHID + h] * xv;  // scalar loads
  }
  #pragma unroll
  for (int i = 0; i < 4; ++i) {
    int c = c0 + i, n = c / HD, d = c % HD;
    kT[(((size_t)(b * NH + n)) * HD + d) * LL + l] = acc[i];      // coalesced
  }
}

// ---- K1b: esj = exp((k.w2)*scale); row factor exp(si) cancels in softmax ----
__global__ __launch_bounds__(256) void k_edgeproj(
    const float* __restrict__ kT, const float* __restrict__ we_w,
    float* __restrict__ esj) {
  const int idx = blockIdx.x * 256 + threadIdx.x;   // over B*NH*L = 40960
  const int bn = idx >> 10, l = idx & (LL - 1);
  const float* kp = kT + (size_t)bn * HD * LL + l;
  float s2 = 0.f;
  #pragma unroll
  for (int d = 0; d < HD; ++d) s2 += kp[(size_t)d * LL] * we_w[HD + d];  // coalesced
  esj[idx] = __expf(s2 * SCALE);
}

// ---- K1c: pack edge row (1024 int32 = 4 KB) -> 32 uints (128 B) of nibbles.
// Layout: pm[row*32 + m*8 + (lane>>3)], nibble at bit (lane&7)*4 holds
// edge bits for j = m*256 + lane*4 + {0,1,2,3}. One block per row; wave w = m.
__global__ __launch_bounds__(256) void k_packmask(
    const int* __restrict__ edge, unsigned* __restrict__ pm) {
  const int row  = blockIdx.x;           // 0 .. B*L-1
  const int lane = threadIdx.x & 63;
  const int m    = threadIdx.x >> 6;     // 0..3
  int4 e = ((const int4*)(edge + (size_t)row * LL))[m * 64 + lane];  // coalesced
  unsigned v = ((e.x ? 1u : 0u) | (e.y ? 2u : 0u) | (e.z ? 4u : 0u) | (e.w ? 8u : 0u))
               << ((lane & 7) * 4);
  v |= __shfl_xor(v, 1, 64);             // OR-combine 8-lane aligned groups
  v |= __shfl_xor(v, 2, 64);
  v |= __shfl_xor(v, 4, 64);
  if ((lane & 7) == 0)
    pm[row * 32 + m * 8 + (lane >> 3)] = v;
}

// ---- K2: fused mask+softmax+PV, exp-free; edge via 512 KB packed bitmask ----
// alpha[i,j] = mask[i,j]*esj[j] / sum_j mask[i,j]*esj[j]
// block = 512 (8 waves), 1 head, 4 rows/wave -> 32 rows/block, grid 1280.
__global__ __launch_bounds__(512) void k_attn(
    const float* __restrict__ kT, const float* __restrict__ esj,
    const unsigned* __restrict__ pm,
    float* __restrict__ alpha_out, float* __restrict__ att) {
  const int t    = threadIdx.x;
  const int lane = t & 63;
  const int wid  = t >> 6;
  const int blk  = blockIdx.x;
  const int rt   = blk & 31;        // 32 row-tiles
  const int bn   = blk >> 5;
  const int b    = bn / NH;
  const int i0   = rt * 32 + wid * 4;

  __shared__ float ksT[HD * LL];    // 40 KB: kT[b,n,:,:] (d-major, stride-1 in j)
  {
    const float4* src = (const float4*)(kT + (size_t)bn * (HD * LL));
    float4* dst = (float4*)ksT;
    #pragma unroll
    for (int idx = t; idx < (HD * LL) / 4; idx += 512) dst[idx] = src[idx];
  }
  vfloat4 esv[4];                   // esj, j = m*256 + lane*4 + q
  {
    const vfloat4* sp = (const vfloat4*)(esj + (size_t)bn * LL);
    #pragma unroll
    for (int m = 0; m < 4; ++m) esv[m] = sp[m * 64 + lane];
  }
  // packed masks: 4 L1/L2-hot dword gathers per row (128 B/row, reused 10x)
  const int s4 = (lane & 7) * 4;
  unsigned mku[4][4];
  #pragma unroll
  for (int r = 0; r < 4; ++r) {
    const unsigned* pmrow = pm + ((size_t)b * LL + (i0 + r)) * 32 + (lane >> 3);
    #pragma unroll
    for (int m = 0; m < 4; ++m) mku[r][m] = pmrow[m * 8];
  }
  __syncthreads();

  // ---- phase 1: denominators + unnormalized PV ----
  float part[4][HD];
  float denom[4];
  #pragma unroll
  for (int r = 0; r < 4; ++r) {
    denom[r] = 0.f;
    #pragma unroll
    for (int d = 0; d < HD; ++d) part[r][d] = 0.f;
  }
  #pragma unroll
  for (int m = 0; m < 4; ++m) {
    vfloat4 kv[HD];                       // conflict-free ds_read_b128
    const float* kb = ksT + m * 256 + lane * 4;
    #pragma unroll
    for (int d = 0; d < HD; ++d) kv[d] = *(const vfloat4*)(kb + d * LL);
    const vfloat4 es = esv[m];
    #pragma unroll
    for (int r = 0; r < 4; ++r) {
      const unsigned mk = mku[r][m] >> s4;
      float ax = (mk & 1u) ? es.x : 0.f;
      float ay = (mk & 2u) ? es.y : 0.f;
      float az = (mk & 4u) ? es.z : 0.f;
      float aw = (mk & 8u) ? es.w : 0.f;
      denom[r] += (ax + ay) + (az + aw);
      #pragma unroll
      for (int d = 0; d < HD; ++d)
        part[r][d] += ax * kv[d].x + ay * kv[d].y + az * kv[d].z + aw * kv[d].w;
    }
  }
  float inv[4];
  #pragma unroll
  for (int r = 0; r < 4; ++r) {
    float s = denom[r];
    #pragma unroll
    for (int sft = 32; sft >= 1; sft >>= 1) s += __shfl_xor(s, sft, 64);
    inv[r] = __builtin_amdgcn_rcpf(s);
  }

  // ---- phase 2: alpha stores from mask bits (plain dwordx4) ----
  float* ap = alpha_out + ((size_t)bn * LL + i0) * LL;
  #pragma unroll
  for (int m = 0; m < 4; ++m) {
    const vfloat4 es = esv[m];
    #pragma unroll
    for (int r = 0; r < 4; ++r) {
      const unsigned mk = mku[r][m] >> s4;
      vfloat4 a;
      a.x = (mk & 1u) ? es.x * inv[r] : 0.f;
      a.y = (mk & 2u) ? es.y * inv[r] : 0.f;
      a.z = (mk & 4u) ? es.z * inv[r] : 0.f;
      a.w = (mk & 8u) ? es.w * inv[r] : 0.f;
      *((vfloat4*)(ap + (size_t)r * LL) + m * 64 + lane) = a;
    }
  }

  // ---- PV reduce-scatter: 17 shuffles per row (values padded to 16) ----
  const bool c5 = (lane & 32) != 0;
  const bool c4 = (lane & 16) != 0;
  const bool c3 = (lane & 8) != 0;
  const bool c2 = (lane & 4) != 0;
  #pragma unroll
  for (int r = 0; r < 4; ++r) {
    float pv[16];
    #pragma unroll
    for (int d = 0; d < HD; ++d) pv[d] = part[r][d];
    #pragma unroll
    for (int d = HD; d < 16; ++d) pv[d] = 0.f;
    #pragma unroll
    for (int i = 0; i < 8; ++i) {
      float snd = c5 ? pv[i] : pv[i + 8];
      float kp  = c5 ? pv[i + 8] : pv[i];
      pv[i] = kp + __shfl_xor(snd, 32, 64);
    }
    #pragma unroll
    for (int i = 0; i < 4; ++i) {
      float snd = c4 ? pv[i] : pv[i + 4];
      float kp  = c4 ? pv[i + 4] : pv[i];
      pv[i] = kp + __shfl_xor(snd, 16, 64);
    }
    #pragma unroll
    for (int i = 0; i < 2; ++i) {
      float snd = c3 ? pv[i] : pv[i + 2];
      float kp  = c3 ? pv[i + 2] : pv[i];
      pv[i] = kp + __shfl_xor(snd, 8, 64);
    }
    {
      float snd = c2 ? pv[0] : pv[1];
      float kp  = c2 ? pv[1] : pv[0];
      pv[0] = kp + __shfl_xor(snd, 4, 64);
    }
    pv[0] += __shfl_xor(pv[0], 2, 64);
    pv[0] += __shfl_xor(pv[0], 1, 64);
    float g = __shfl(pv[0], lane * 4, 64);   // lane l holds d=(l>>2)&15
    if (lane < HD)
      att[((size_t)bn * LL + (i0 + r)) * HD + lane] = g * inv[r];
  }
}

// ---------------- K3: output projection over scrambled view ----------------
__global__ __launch_bounds__(256) void k_out(
    const float* __restrict__ att, const float* __restrict__ wo_w,
    const float* __restrict__ wo_b, float* __restrict__ ret) {
  const int l  = blockIdx.x * 256 + threadIdx.x;
  const int o0 = blockIdx.y * 4;
  const int b  = blockIdx.z;
  const float* ab = att + (size_t)b * (DD * LL);
  float acc[4];
  #pragma unroll
  for (int oo = 0; oo < 4; ++oo) acc[oo] = wo_b[o0 + oo];
  for (int c = 0; c < DD; ++c) {
    float a = ab[(size_t)c * LL + l];          // coalesced; view(B,-1,L) == linear index
    #pragma unroll
    for (int oo = 0; oo < 4; ++oo) acc[oo] += wo_w[(size_t)(o0 + oo) * DD + c] * a;
  }
  #pragma unroll
  for (int oo = 0; oo < 4; ++oo)
    ret[((size_t)b * NHID + o0 + oo) * LL + l] = acc[oo];
}

extern "C" void kernel_launch(void* const* d_in, const int* in_sizes, int n_in,
                              void* d_out, int out_size, void* d_ws, size_t ws_size,
                              hipStream_t stream) {
  (void)in_sizes; (void)n_in; (void)out_size; (void)ws_size;
  const float* x    = (const float*)d_in[0];
  const int*   edge = (const int*)d_in[1];
  const float* wq_w = (const float*)d_in[2];
  const float* wq_b = (const float*)d_in[3];
  const float* we_w = (const float*)d_in[4];
  const float* wo_w = (const float*)d_in[6];
  const float* wo_b = (const float*)d_in[7];

  float* out       = (float*)d_out;
  float* ret_out   = out;                                  // B*NHID*L
  float* alpha_out = out + (size_t)BB * NHID * LL;         // B*NH*L*L

  float* ws   = (float*)d_ws;
  float* kT   = ws;                                        // B*NH*HD*L = 409600
  float* esj  = kT + (size_t)BB * NH * HD * LL;            // B*NH*L
  float* att  = esj + (size_t)BB * NH * LL;                // B*NH*L*HD
  unsigned* pmask = (unsigned*)(att + (size_t)BB * NH * LL * HD);  // B*L*32 uints

  k_packmask<<<BB * LL, 256, 0, stream>>>(edge, pmask);

  dim3 g1(LL / 256, DD / 4, BB);
  k_qproj<<<g1, 256, 0, stream>>>(x, wq_w, wq_b, kT);

  k_edgeproj<<<(BB * NH * LL) / 256, 256, 0, stream>>>(kT, we_w, esj);

  k_attn<<<BB * NH * (LL / 32), 512, 0, stream>>>(kT, esj, pmask, alpha_out, att);

  dim3 g3(LL / 256, NHID / 4, BB);
  k_out<<<g3, 256, 0, stream>>>(att, wo_w, wo_b, ret_out);
}